// Round 3
// baseline (170.417 us; speedup 1.0000x reference)
//
#include <hip/hip_runtime.h>
#include <math.h>

#define BATCH 32
#define LEN   2048
#define HID   128
#define SSM   256

static const size_t PLz = 16777216;   // elements per state plane (32*256*2048)
#define BPL 32768                     // elements per B-split plane (256*128)
#define CPL 32768                     // elements per C-split plane (128*256)

typedef __attribute__((ext_vector_type(4))) float f32x4;
typedef __attribute__((ext_vector_type(8))) short bf16x8;
typedef __attribute__((ext_vector_type(4))) short bf16x4;
typedef __attribute__((ext_vector_type(4))) int   i32x4;

// f32 -> bf16 round-to-nearest-even (bit trick, valid for finite values)
static __device__ __forceinline__ unsigned short f2bf(float x) {
    union { float f; unsigned u; } v; v.f = x;
    unsigned r = (v.u + 0x7FFFu + ((v.u >> 16) & 1u)) >> 16;
    return (unsigned short)r;
}
static __device__ __forceinline__ float bf2f(unsigned short b) {
    union { unsigned u; float f; } v; v.u = ((unsigned)b) << 16;
    return v.f;
}
// complex multiply (out must not alias in — callers pass temps)
static __device__ __forceinline__ void cmul(float& rr, float& ri,
                                            float ar, float ai, float br, float bi) {
    rr = ar * br - ai * bi;
    ri = ar * bi + ai * br;
}

// ---------------------------------------------------------------------------
// K0: parameter projection + eigenvalue. lam[0..255]=re, lam[256..511]=im.
// ---------------------------------------------------------------------------
__global__ void k0_params(const float* __restrict__ A, const float* __restrict__ G,
                          const float* __restrict__ steps, float* __restrict__ lam) {
    int p = threadIdx.x;
    if (p < SSM) {
        float stp   = 1.f / (1.f + expf(-steps[p]));
        float g     = fmaxf(G[p], 0.f);
        float denom = fmaxf(stp * stp, 1e-6f);
        float s     = stp * g;
        float base  = sqrtf(fmaxf(1.f + s, 1e-6f));
        float alow  = (2.f + s - 2.f * base) / denom;
        float ahigh = (2.f + s + 2.f * base) / denom;
        float a     = alow + fmaxf(A[p] - alow, 0.f) - fmaxf(A[p] - ahigh, 0.f);
        float S     = 1.f / (1.f + stp * g);
        float T     = S + 1.f - stp * stp * S * a;
        lam[p]       = 0.5f * T;
        lam[SSM + p] = sqrtf(fmaxf(S - 0.25f * T * T, 0.f));
    }
}

// ---------------------------------------------------------------------------
// K0b: pre-split B and C into hi/lo bf16 planes.
// Bsp planes: [re_hi, re_lo, im_hi, im_lo], layout [p][h]
// Csp planes: [re_hi, re_lo, nim_hi, nim_lo] (imag NEGATED), layout [h][p]
// ---------------------------------------------------------------------------
__global__ __launch_bounds__(256) void k0b_prep(const float* __restrict__ Bm,
                                                const float* __restrict__ Cm,
                                                unsigned short* __restrict__ Bsp,
                                                unsigned short* __restrict__ Csp) {
    int gidx = blockIdx.x * 256 + threadIdx.x;
    if (gidx < 32768) {
        int p = gidx >> 7, h = gidx & 127;
        float vr = Bm[(size_t)(p * HID + h) * 2];
        float vi = Bm[(size_t)(p * HID + h) * 2 + 1];
        unsigned short hh = f2bf(vr);
        Bsp[0 * BPL + p * HID + h] = hh;
        Bsp[1 * BPL + p * HID + h] = f2bf(vr - bf2f(hh));
        hh = f2bf(vi);
        Bsp[2 * BPL + p * HID + h] = hh;
        Bsp[3 * BPL + p * HID + h] = f2bf(vi - bf2f(hh));
    } else {
        int g2 = gidx - 32768;
        int h = g2 >> 8, p = g2 & 255;
        float vr = Cm[(size_t)(h * SSM + p) * 2];
        float vi = -Cm[(size_t)(h * SSM + p) * 2 + 1];
        unsigned short hh = f2bf(vr);
        Csp[0 * CPL + h * SSM + p] = hh;
        Csp[1 * CPL + h * SSM + p] = f2bf(vr - bf2f(hh));
        hh = f2bf(vi);
        Csp[2 * CPL + h * SSM + p] = hh;
        Csp[3 * CPL + h * SSM + p] = f2bf(vi - bf2f(hh));
    }
}

// ---------------------------------------------------------------------------
// K12 (fused): per block = (32 p-columns, one b). Iterates 16 l-tiles of 128:
//   stage u tile (f32 -> bf16 hi/lo in LDS), split-bf16 MFMA GEMM (bu),
//   hierarchical complex scan IN FRAGMENT LAYOUT, write states hi/lo planes.
// 4 waves stacked along l (wave w = rows w*32..w*32+31 of the tile).
// Fragment map (verified m89): col(p) = lane&15, row(l) = (lane>>4)*4 + reg.
// ---------------------------------------------------------------------------
__global__ __launch_bounds__(256, 1) void k12_fused(const float* __restrict__ u,
                                                    const unsigned short* __restrict__ Bsp,
                                                    const float* __restrict__ lam,
                                                    unsigned short* __restrict__ planes) {
    __shared__ __align__(16) unsigned short sU[2][128][136];  // [plane][l][h(+pad)]
    __shared__ float Rld[4][2][16][2];                        // [wave][ni][fr][re/im]

    int tid  = threadIdx.x;
    int lane = tid & 63, w = tid >> 6;
    int fr   = lane & 15, g = lane >> 4;
    int p0   = blockIdx.x * 32;
    int b    = blockIdx.y;

    // ---- B fragments -> registers: [plane][ni][kchunk] ----
    bf16x8 Bf[4][2][4];
#pragma unroll
    for (int pl = 0; pl < 4; ++pl)
#pragma unroll
        for (int ni = 0; ni < 2; ++ni)
#pragma unroll
            for (int kc = 0; kc < 4; ++kc)
                Bf[pl][ni][kc] = *(const bf16x8*)&Bsp[(size_t)pl * BPL +
                        (size_t)(p0 + ni * 16 + fr) * HID + kc * 32 + g * 8];

    // ---- lambda powers per lane (for its 2 p-columns) ----
    float pw_r[2][4], pw_i[2][4];          // lam^(r+1), r=0..3
    float lg_r[2], lg_i[2];                // lam^(4g)
    float l4r[2], l4i[2], l8r[2], l8i[2];
    float l16r[2], l16i[2], l32r[2], l32i[2];
#pragma unroll
    for (int ni = 0; ni < 2; ++ni) {
        int p = p0 + ni * 16 + fr;
        float ar = lam[p], ai = lam[SSM + p];
        pw_r[ni][0] = ar; pw_i[ni][0] = ai;
        cmul(pw_r[ni][1], pw_i[ni][1], ar, ai, ar, ai);
        cmul(pw_r[ni][2], pw_i[ni][2], pw_r[ni][1], pw_i[ni][1], ar, ai);
        cmul(pw_r[ni][3], pw_i[ni][3], pw_r[ni][1], pw_i[ni][1], pw_r[ni][1], pw_i[ni][1]);
        l4r[ni] = pw_r[ni][3]; l4i[ni] = pw_i[ni][3];
        cmul(l8r[ni], l8i[ni], l4r[ni], l4i[ni], l4r[ni], l4i[ni]);
        cmul(l16r[ni], l16i[ni], l8r[ni], l8i[ni], l8r[ni], l8i[ni]);
        cmul(l32r[ni], l32i[ni], l16r[ni], l16i[ni], l16r[ni], l16i[ni]);
        if (g == 0)      { lg_r[ni] = 1.f;      lg_i[ni] = 0.f; }
        else if (g == 1) { lg_r[ni] = l4r[ni];  lg_i[ni] = l4i[ni]; }
        else if (g == 2) { lg_r[ni] = l8r[ni];  lg_i[ni] = l8i[ni]; }
        else             { cmul(lg_r[ni], lg_i[ni], l8r[ni], l8i[ni], l4r[ni], l4i[ni]); }
    }

    float TCr[2] = {0.f, 0.f}, TCi[2] = {0.f, 0.f};   // running tile carry per ni

    int srow  = tid >> 1;
    int hbase = (tid & 1) * 64;

    for (int t = 0; t < 16; ++t) {
        int l0t = t * 128;
        __syncthreads();   // protect sU reuse (prev tile's frag reads done)

        // ---- stage u tile: 128 l x 128 h, f32 -> hi/lo bf16 ----
        {
            const float* usrc = &u[((size_t)b * LEN + l0t + srow) * HID + hbase];
            f32x4 tmp[16];
#pragma unroll
            for (int q = 0; q < 16; ++q) tmp[q] = *(const f32x4*)&usrc[q * 4];
#pragma unroll
            for (int q = 0; q < 16; ++q) {
                bf16x4 hv, lv;
#pragma unroll
                for (int e = 0; e < 4; ++e) {
                    unsigned short hh = f2bf(tmp[q][e]);
                    hv[e] = (short)hh;
                    lv[e] = (short)f2bf(tmp[q][e] - bf2f(hh));
                }
                int hofs = hbase + q * 4;
                *(bf16x4*)&sU[0][srow][hofs] = hv;
                *(bf16x4*)&sU[1][srow][hofs] = lv;
            }
        }
        __syncthreads();

        // ---- GEMM: bu fragments for this wave's 32 l-rows ----
        f32x4 accr[2][2], acci[2][2];
#pragma unroll
        for (int mi = 0; mi < 2; ++mi)
#pragma unroll
            for (int ni = 0; ni < 2; ++ni) { accr[mi][ni] = (f32x4)(0.f); acci[mi][ni] = (f32x4)(0.f); }

#pragma unroll
        for (int kc = 0; kc < 4; ++kc) {
#pragma unroll
            for (int mi = 0; mi < 2; ++mi) {
                int row = w * 32 + mi * 16 + fr;
                bf16x8 ah = *(const bf16x8*)&sU[0][row][kc * 32 + g * 8];
                bf16x8 al = *(const bf16x8*)&sU[1][row][kc * 32 + g * 8];
#pragma unroll
                for (int ni = 0; ni < 2; ++ni) {
                    accr[mi][ni] = __builtin_amdgcn_mfma_f32_16x16x32_bf16(ah, Bf[0][ni][kc], accr[mi][ni], 0, 0, 0);
                    accr[mi][ni] = __builtin_amdgcn_mfma_f32_16x16x32_bf16(ah, Bf[1][ni][kc], accr[mi][ni], 0, 0, 0);
                    accr[mi][ni] = __builtin_amdgcn_mfma_f32_16x16x32_bf16(al, Bf[0][ni][kc], accr[mi][ni], 0, 0, 0);
                    acci[mi][ni] = __builtin_amdgcn_mfma_f32_16x16x32_bf16(ah, Bf[2][ni][kc], acci[mi][ni], 0, 0, 0);
                    acci[mi][ni] = __builtin_amdgcn_mfma_f32_16x16x32_bf16(ah, Bf[3][ni][kc], acci[mi][ni], 0, 0, 0);
                    acci[mi][ni] = __builtin_amdgcn_mfma_f32_16x16x32_bf16(al, Bf[2][ni][kc], acci[mi][ni], 0, 0, 0);
                }
            }
        }

        // ---- scan, phase 1 (pre-barrier): local scans + raw wave carry ----
        float Er[2][2], Ei[2][2];   // [mi][ni] within-frag exclusive quad carry
        float Fr[2][2], Fi[2][2];   // [mi][ni] raw frag carry (rows 0..15 of frag)
#pragma unroll
        for (int ni = 0; ni < 2; ++ni) {
            float lr = pw_r[ni][0], li = pw_i[ni][0];
            float Qr[2], Qi[2];
            // step 1: serial scan within each r-quad
#pragma unroll
            for (int mi = 0; mi < 2; ++mi) {
                float xr = 0.f, xi = 0.f;
#pragma unroll
                for (int r = 0; r < 4; ++r) {
                    float nr = fmaf(lr, xr, fmaf(-li, xi, accr[mi][ni][r]));
                    float nx = fmaf(lr, xi, fmaf(li, xr, acci[mi][ni][r]));
                    xr = nr; xi = nx;
                    accr[mi][ni][r] = xr; acci[mi][ni][r] = xi;
                }
                Qr[mi] = xr; Qi[mi] = xi;
            }
            // step 2: Hillis-Steele across g (quad carries), multipliers lam^4, lam^8
#pragma unroll
            for (int mi = 0; mi < 2; ++mi) {
                float ur = __shfl_up(Qr[mi], 16u, 64);
                float ui = __shfl_up(Qi[mi], 16u, 64);
                if (g >= 1) {
                    Qr[mi] = fmaf(l4r[ni], ur, fmaf(-l4i[ni], ui, Qr[mi]));
                    Qi[mi] = fmaf(l4r[ni], ui, fmaf(l4i[ni], ur, Qi[mi]));
                }
                ur = __shfl_up(Qr[mi], 32u, 64);
                ui = __shfl_up(Qi[mi], 32u, 64);
                if (g >= 2) {
                    Qr[mi] = fmaf(l8r[ni], ur, fmaf(-l8i[ni], ui, Qr[mi]));
                    Qi[mi] = fmaf(l8r[ni], ui, fmaf(l8i[ni], ur, Qi[mi]));
                }
                // exclusive carry for this lane's quad
                float er = __shfl_up(Qr[mi], 16u, 64);
                float ei = __shfl_up(Qi[mi], 16u, 64);
                if (g == 0) { er = 0.f; ei = 0.f; }
                Er[mi][ni] = er; Ei[mi][ni] = ei;
                // frag carry = inclusive value at g=3, broadcast to all g
                Fr[mi][ni] = __shfl(Qr[mi], fr + 48, 64);
                Fi[mi][ni] = __shfl(Qi[mi], fr + 48, 64);
            }
            // raw wave carry R = F1 + lam^16 * F0
            float Rr = fmaf(l16r[ni], Fr[0][ni], fmaf(-l16i[ni], Fi[0][ni], Fr[1][ni]));
            float Ri = fmaf(l16r[ni], Fi[0][ni], fmaf(l16i[ni], Fr[0][ni], Fi[1][ni]));
            if (g == 0) { Rld[w][ni][fr][0] = Rr; Rld[w][ni][fr][1] = Ri; }
        }
        __syncthreads();

        // ---- scan, phase 2: cross-wave carry, tile carry, corrections, store ----
#pragma unroll
        for (int ni = 0; ni < 2; ++ni) {
            float Wr = TCr[ni], Wi = TCi[ni];   // carry entering this wave
            float Tr = TCr[ni], Ti = TCi[ni];   // next tile carry
#pragma unroll
            for (int w2 = 0; w2 < 4; ++w2) {
                float rr = Rld[w2][ni][fr][0], ri = Rld[w2][ni][fr][1];
                float nTr = fmaf(l32r[ni], Tr, fmaf(-l32i[ni], Ti, rr));
                float nTi = fmaf(l32r[ni], Ti, fmaf(l32i[ni], Tr, ri));
                Tr = nTr; Ti = nTi;
                if (w2 < w) {
                    float nWr = fmaf(l32r[ni], Wr, fmaf(-l32i[ni], Wi, rr));
                    float nWi = fmaf(l32r[ni], Wi, fmaf(l32i[ni], Wr, ri));
                    Wr = nWr; Wi = nWi;
                }
            }
            TCr[ni] = Tr; TCi[ni] = Ti;
            // pre(0)=W ; pre(1)=lam^16*W + F0
            float p1r = fmaf(l16r[ni], Wr, fmaf(-l16i[ni], Wi, Fr[0][ni]));
            float p1i = fmaf(l16r[ni], Wi, fmaf(l16i[ni], Wr, Fi[0][ni]));
#pragma unroll
            for (int mi = 0; mi < 2; ++mi) {
                float prr = (mi == 0) ? Wr : p1r;
                float pri = (mi == 0) ? Wi : p1i;
                // M = E + lam^(4g) * pre ; then x[r] += lam^(r+1) * M
                float Mr = fmaf(lg_r[ni], prr, fmaf(-lg_i[ni], pri, Er[mi][ni]));
                float Mi = fmaf(lg_r[ni], pri, fmaf(lg_i[ni], prr, Ei[mi][ni]));
#pragma unroll
                for (int r = 0; r < 4; ++r) {
                    accr[mi][ni][r] = fmaf(pw_r[ni][r], Mr, fmaf(-pw_i[ni][r], Mi, accr[mi][ni][r]));
                    acci[mi][ni][r] = fmaf(pw_r[ni][r], Mi, fmaf(pw_i[ni][r], Mr, acci[mi][ni][r]));
                }
            }
        }

        // ---- store states as hi/lo bf16 planes ----
#pragma unroll
        for (int mi = 0; mi < 2; ++mi)
#pragma unroll
            for (int ni = 0; ni < 2; ++ni) {
                int pcol = p0 + ni * 16 + fr;
                int lrow = l0t + w * 32 + mi * 16 + g * 4;
                size_t idx = ((size_t)(b * SSM + pcol)) * LEN + lrow;
                bf16x4 rh, rl, ih, il;
#pragma unroll
                for (int e = 0; e < 4; ++e) {
                    unsigned short hh = f2bf(accr[mi][ni][e]);
                    rh[e] = (short)hh; rl[e] = (short)f2bf(accr[mi][ni][e] - bf2f(hh));
                    hh = f2bf(acci[mi][ni][e]);
                    ih[e] = (short)hh; il[e] = (short)f2bf(acci[mi][ni][e] - bf2f(hh));
                }
                *(bf16x4*)&planes[0 * PLz + idx] = rh;
                *(bf16x4*)&planes[1 * PLz + idx] = rl;
                *(bf16x4*)&planes[2 * PLz + idx] = ih;
                *(bf16x4*)&planes[3 * PLz + idx] = il;
            }
    }
}

// ---------------------------------------------------------------------------
// K3 (MFMA): out[b][l][h] = sum_p s_re*C_re - s_im*C_im + u*D   (unchanged)
// ---------------------------------------------------------------------------
__global__ __launch_bounds__(256) void k3_out(const unsigned short* __restrict__ planes,
                                              const unsigned short* __restrict__ Csp,
                                              const float* __restrict__ u,
                                              const float* __restrict__ D,
                                              float* __restrict__ out) {
    __shared__ __align__(16) unsigned short sA[4][128][40];
    __shared__ __align__(16) unsigned short sC[4][128][40];
    int tid = threadIdx.x;
    int l0 = blockIdx.x * 128, b = blockIdx.y;
    int lane = tid & 63, w = tid >> 6;
    int wl = w >> 1, wh = w & 1;
    int fr = lane & 15, g = lane >> 4;

    f32x4 acc[4][4];
#pragma unroll
    for (int mi = 0; mi < 4; ++mi)
#pragma unroll
        for (int ni = 0; ni < 4; ++ni) acc[mi][ni] = (f32x4)(0.f);

    float dv[4];
#pragma unroll
    for (int ni = 0; ni < 4; ++ni) dv[ni] = D[wh * 64 + ni * 16 + fr];

    for (int pc = 0; pc < SSM; pc += 32) {
        {
            int loct = tid & 15;
#pragma unroll
            for (int r = 0; r < 2; ++r) {
                int p_ = (tid >> 4) + 16 * r;
                int rot = (loct + p_) & 7;
#pragma unroll
                for (int pl = 0; pl < 4; ++pl) {
                    union { bf16x8 v; unsigned long long q[2]; } U;
                    U.v = *(const bf16x8*)&planes[(size_t)pl * PLz +
                            ((size_t)(b * SSM + pc + p_)) * LEN + l0 + loct * 8];
                    unsigned long long x0 = U.q[0], x1 = U.q[1];
                    if (rot & 4) { unsigned long long tq = x0; x0 = x1; x1 = tq; }
                    if (rot & 2) {
                        unsigned long long n0 = (x0 >> 32) | (x1 << 32);
                        unsigned long long n1 = (x1 >> 32) | (x0 << 32);
                        x0 = n0; x1 = n1;
                    }
                    if (rot & 1) {
                        unsigned long long n0 = (x0 >> 16) | (x1 << 48);
                        unsigned long long n1 = (x1 >> 16) | (x0 << 48);
                        x0 = n0; x1 = n1;
                    }
                    int rb = loct * 8;
                    sA[pl][rb + ((0 + rot) & 7)][p_] = (unsigned short)(x0);
                    sA[pl][rb + ((1 + rot) & 7)][p_] = (unsigned short)(x0 >> 16);
                    sA[pl][rb + ((2 + rot) & 7)][p_] = (unsigned short)(x0 >> 32);
                    sA[pl][rb + ((3 + rot) & 7)][p_] = (unsigned short)(x0 >> 48);
                    sA[pl][rb + ((4 + rot) & 7)][p_] = (unsigned short)(x1);
                    sA[pl][rb + ((5 + rot) & 7)][p_] = (unsigned short)(x1 >> 16);
                    sA[pl][rb + ((6 + rot) & 7)][p_] = (unsigned short)(x1 >> 32);
                    sA[pl][rb + ((7 + rot) & 7)][p_] = (unsigned short)(x1 >> 48);
                }
            }
        }
        {
            int poct = tid & 3;
#pragma unroll
            for (int r2 = 0; r2 < 2; ++r2) {
                int hh = (tid >> 2) + 64 * r2;
#pragma unroll
                for (int pl = 0; pl < 4; ++pl) {
                    i32x4 v = *(const i32x4*)&Csp[(size_t)pl * CPL + (size_t)hh * SSM + pc + poct * 8];
                    *(i32x4*)&sC[pl][hh][poct * 8] = v;
                }
            }
        }
        __syncthreads();

        int kk = g * 8;
        bf16x8 crh[4], crl[4], cih[4], cil[4];
#pragma unroll
        for (int ni = 0; ni < 4; ++ni) {
            int hr = wh * 64 + ni * 16 + fr;
            crh[ni] = *(const bf16x8*)&sC[0][hr][kk];
            crl[ni] = *(const bf16x8*)&sC[1][hr][kk];
            cih[ni] = *(const bf16x8*)&sC[2][hr][kk];
            cil[ni] = *(const bf16x8*)&sC[3][hr][kk];
        }
#pragma unroll
        for (int mi = 0; mi < 4; ++mi) {
            int lr_ = wl * 64 + mi * 16 + fr;
            bf16x8 arh = *(const bf16x8*)&sA[0][lr_][kk];
            bf16x8 arl = *(const bf16x8*)&sA[1][lr_][kk];
            bf16x8 aih = *(const bf16x8*)&sA[2][lr_][kk];
            bf16x8 ail = *(const bf16x8*)&sA[3][lr_][kk];
#pragma unroll
            for (int ni = 0; ni < 4; ++ni) {
                acc[mi][ni] = __builtin_amdgcn_mfma_f32_16x16x32_bf16(arh, crh[ni], acc[mi][ni], 0, 0, 0);
                acc[mi][ni] = __builtin_amdgcn_mfma_f32_16x16x32_bf16(arh, crl[ni], acc[mi][ni], 0, 0, 0);
                acc[mi][ni] = __builtin_amdgcn_mfma_f32_16x16x32_bf16(arl, crh[ni], acc[mi][ni], 0, 0, 0);
                acc[mi][ni] = __builtin_amdgcn_mfma_f32_16x16x32_bf16(aih, cih[ni], acc[mi][ni], 0, 0, 0);
                acc[mi][ni] = __builtin_amdgcn_mfma_f32_16x16x32_bf16(aih, cil[ni], acc[mi][ni], 0, 0, 0);
                acc[mi][ni] = __builtin_amdgcn_mfma_f32_16x16x32_bf16(ail, cih[ni], acc[mi][ni], 0, 0, 0);
            }
        }
        __syncthreads();
    }

#pragma unroll
    for (int mi = 0; mi < 4; ++mi)
#pragma unroll
        for (int ni = 0; ni < 4; ++ni) {
            int lb = l0 + wl * 64 + mi * 16 + g * 4;
            int h = wh * 64 + ni * 16 + fr;
#pragma unroll
            for (int r = 0; r < 4; ++r) {
                size_t idx = ((size_t)b * LEN + lb + r) * HID + h;
                out[idx] = acc[mi][ni][r] + u[idx] * dv[ni];
            }
        }
}

// ---------------------------------------------------------------------------
// Workspace layout (bytes):
//   [0, 134217728)             4 bf16 state planes
//   [134217728, 134219776)     lam (512 f32)
//   [134219776, 134481920)     B split planes (4 x 32768 ushort)
//   [134481920, 134744064)     C split planes (4 x 32768 ushort)
// ---------------------------------------------------------------------------
extern "C" void kernel_launch(void* const* d_in, const int* in_sizes, int n_in,
                              void* d_out, int out_size, void* d_ws, size_t ws_size,
                              hipStream_t stream) {
    const float* u  = (const float*)d_in[0];
    const float* A  = (const float*)d_in[1];
    const float* G  = (const float*)d_in[2];
    const float* st = (const float*)d_in[3];
    const float* B  = (const float*)d_in[4];
    const float* C  = (const float*)d_in[5];
    const float* D  = (const float*)d_in[6];
    float* out = (float*)d_out;

    char* WS = (char*)d_ws;
    unsigned short* planes = (unsigned short*)WS;
    float* lam             = (float*)(WS + 134217728);
    unsigned short* Bsp    = (unsigned short*)(WS + 134219776);
    unsigned short* Csp    = (unsigned short*)(WS + 134481920);

    k0_params<<<1, 256, 0, stream>>>(A, G, st, lam);
    k0b_prep<<<256, 256, 0, stream>>>(B, C, Bsp, Csp);
    k12_fused<<<dim3(8, 32), 256, 0, stream>>>(u, Bsp, lam, planes);
    k3_out<<<dim3(16, 32), 256, 0, stream>>>(planes, Csp, u, D, out);
}

// Round 4
// 144.948 us; speedup vs baseline: 1.1757x; 1.1757x over previous
//
#include <hip/hip_runtime.h>
#include <math.h>

#define BATCH 32
#define LEN   2048
#define HID   128
#define SSM   256

static const size_t PLz = 16777216;   // elements per state plane (32*256*2048)
#define BPL 32768                     // elements per B-split plane (256*128)
#define CPL 32768                     // elements per C-split plane (128*256)

typedef __attribute__((ext_vector_type(4))) float f32x4;
typedef __attribute__((ext_vector_type(8))) short bf16x8;
typedef __attribute__((ext_vector_type(4))) short bf16x4;
typedef __attribute__((ext_vector_type(4))) int   i32x4;

// RNE f32->bf16 (used for lo terms)
static __device__ __forceinline__ unsigned short f2bf(float x) {
    union { float f; unsigned u; } v; v.f = x;
    unsigned r = (v.u + 0x7FFFu + ((v.u >> 16) & 1u)) >> 16;
    return (unsigned short)r;
}
// truncating f32->bf16 (hi term; lo captures the remainder exactly)
static __device__ __forceinline__ unsigned short f2bf_hi(float x) {
    union { float f; unsigned u; } v; v.f = x;
    return (unsigned short)(v.u >> 16);
}
static __device__ __forceinline__ float bf2f(unsigned short b) {
    union { unsigned u; float f; } v; v.u = ((unsigned)b) << 16;
    return v.f;
}
static __device__ __forceinline__ void cmul(float& rr, float& ri,
                                            float ar, float ai, float br, float bi) {
    rr = ar * br - ai * bi;
    ri = ar * bi + ai * br;
}

// ---------------------------------------------------------------------------
// K0: parameter projection + eigenvalue. lam[0..255]=re, lam[256..511]=im.
// ---------------------------------------------------------------------------
__global__ void k0_params(const float* __restrict__ A, const float* __restrict__ G,
                          const float* __restrict__ steps, float* __restrict__ lam) {
    int p = threadIdx.x;
    if (p < SSM) {
        float stp   = 1.f / (1.f + expf(-steps[p]));
        float g     = fmaxf(G[p], 0.f);
        float denom = fmaxf(stp * stp, 1e-6f);
        float s     = stp * g;
        float base  = sqrtf(fmaxf(1.f + s, 1e-6f));
        float alow  = (2.f + s - 2.f * base) / denom;
        float ahigh = (2.f + s + 2.f * base) / denom;
        float a     = alow + fmaxf(A[p] - alow, 0.f) - fmaxf(A[p] - ahigh, 0.f);
        float S     = 1.f / (1.f + stp * g);
        float T     = S + 1.f - stp * stp * S * a;
        lam[p]       = 0.5f * T;
        lam[SSM + p] = sqrtf(fmaxf(S - 0.25f * T * T, 0.f));
    }
}

// ---------------------------------------------------------------------------
// K0b: pre-split B and C into hi/lo bf16 planes.
// Bsp planes: [re_hi, re_lo, im_hi, im_lo], layout [p][h]
// Csp planes: [re_hi, re_lo, nim_hi, nim_lo] (imag NEGATED), layout [h][p]
// ---------------------------------------------------------------------------
__global__ __launch_bounds__(256) void k0b_prep(const float* __restrict__ Bm,
                                                const float* __restrict__ Cm,
                                                unsigned short* __restrict__ Bsp,
                                                unsigned short* __restrict__ Csp) {
    int gidx = blockIdx.x * 256 + threadIdx.x;
    if (gidx < 32768) {
        int p = gidx >> 7, h = gidx & 127;
        float vr = Bm[(size_t)(p * HID + h) * 2];
        float vi = Bm[(size_t)(p * HID + h) * 2 + 1];
        unsigned short hh = f2bf_hi(vr);
        Bsp[0 * BPL + p * HID + h] = hh;
        Bsp[1 * BPL + p * HID + h] = f2bf(vr - bf2f(hh));
        hh = f2bf_hi(vi);
        Bsp[2 * BPL + p * HID + h] = hh;
        Bsp[3 * BPL + p * HID + h] = f2bf(vi - bf2f(hh));
    } else {
        int g2 = gidx - 32768;
        int h = g2 >> 8, p = g2 & 255;
        float vr = Cm[(size_t)(h * SSM + p) * 2];
        float vi = -Cm[(size_t)(h * SSM + p) * 2 + 1];
        unsigned short hh = f2bf_hi(vr);
        Csp[0 * CPL + h * SSM + p] = hh;
        Csp[1 * CPL + h * SSM + p] = f2bf(vr - bf2f(hh));
        hh = f2bf_hi(vi);
        Csp[2 * CPL + h * SSM + p] = hh;
        Csp[3 * CPL + h * SSM + p] = f2bf(vi - bf2f(hh));
    }
}

// ---------------------------------------------------------------------------
// K12 (fused, software-pipelined): per block = (32 p-columns, one b).
// 16 l-tiles of 128. Double-buffered sU; next tile's u loaded to registers
// one iteration ahead (latency hidden under MFMA+scan). Scan math identical
// to the verified round-3 kernel.
// Block swizzle: all 8 p-tiles of one b on one XCD (L2 sharing of u[b]).
// ---------------------------------------------------------------------------
__global__ __launch_bounds__(256, 1) void k12_fused(const float* __restrict__ u,
                                                    const unsigned short* __restrict__ Bsp,
                                                    const float* __restrict__ lam,
                                                    unsigned short* __restrict__ planes) {
    __shared__ __align__(16) unsigned short sU[2][2][128][136];  // [buf][plane][l][h+pad]
    __shared__ float Rld[4][2][16][2];                           // [wave][ni][fr][re/im]

    int d    = blockIdx.x;          // 0..255
    int xcd  = d & 7;
    int grp  = d >> 3;              // 0..31
    int pt   = grp & 7;
    int bhi  = grp >> 3;            // 0..3
    int b    = bhi * 8 + xcd;
    int p0   = pt * 32;

    int tid  = threadIdx.x;
    int lane = tid & 63, w = tid >> 6;
    int fr   = lane & 15, g = lane >> 4;

    // ---- B fragments -> registers: [plane][ni][kchunk] ----
    bf16x8 Bf[4][2][4];
#pragma unroll
    for (int pl = 0; pl < 4; ++pl)
#pragma unroll
        for (int ni = 0; ni < 2; ++ni)
#pragma unroll
            for (int kc = 0; kc < 4; ++kc)
                Bf[pl][ni][kc] = *(const bf16x8*)&Bsp[(size_t)pl * BPL +
                        (size_t)(p0 + ni * 16 + fr) * HID + kc * 32 + g * 8];

    // ---- lambda powers per lane (for its 2 p-columns) ----
    float pw_r[2][4], pw_i[2][4];
    float lg_r[2], lg_i[2];
    float l4r[2], l4i[2], l8r[2], l8i[2];
    float l16r[2], l16i[2], l32r[2], l32i[2];
#pragma unroll
    for (int ni = 0; ni < 2; ++ni) {
        int p = p0 + ni * 16 + fr;
        float ar = lam[p], ai = lam[SSM + p];
        pw_r[ni][0] = ar; pw_i[ni][0] = ai;
        cmul(pw_r[ni][1], pw_i[ni][1], ar, ai, ar, ai);
        cmul(pw_r[ni][2], pw_i[ni][2], pw_r[ni][1], pw_i[ni][1], ar, ai);
        cmul(pw_r[ni][3], pw_i[ni][3], pw_r[ni][1], pw_i[ni][1], pw_r[ni][1], pw_i[ni][1]);
        l4r[ni] = pw_r[ni][3]; l4i[ni] = pw_i[ni][3];
        cmul(l8r[ni], l8i[ni], l4r[ni], l4i[ni], l4r[ni], l4i[ni]);
        cmul(l16r[ni], l16i[ni], l8r[ni], l8i[ni], l8r[ni], l8i[ni]);
        cmul(l32r[ni], l32i[ni], l16r[ni], l16i[ni], l16r[ni], l16i[ni]);
        if (g == 0)      { lg_r[ni] = 1.f;      lg_i[ni] = 0.f; }
        else if (g == 1) { lg_r[ni] = l4r[ni];  lg_i[ni] = l4i[ni]; }
        else if (g == 2) { lg_r[ni] = l8r[ni];  lg_i[ni] = l8i[ni]; }
        else             { cmul(lg_r[ni], lg_i[ni], l8r[ni], l8i[ni], l4r[ni], l4i[ni]); }
    }

    float TCr[2] = {0.f, 0.f}, TCi[2] = {0.f, 0.f};

    const float* ub = u + (size_t)b * (LEN * HID);
    int srow = tid >> 5;            // base row 0..7
    int hcol = (tid & 31) * 4;      // fixed 4-wide h column

    // ---- prologue: load tile 0 into registers (flat, 1KB/wave coalesced) ----
    f32x4 ureg[16];
#pragma unroll
    for (int q = 0; q < 16; ++q)
        ureg[q] = *(const f32x4*)&ub[tid * 4 + q * 1024];

    for (int t = 0; t < 16; ++t) {
        int buf = t & 1;
        int l0t = t * 128;

        // ---- convert ureg (tile t) -> sU[buf] hi/lo ----
#pragma unroll
        for (int q = 0; q < 16; ++q) {
            int row = srow + 8 * q;
            bf16x4 hv, lv;
#pragma unroll
            for (int e = 0; e < 4; ++e) {
                unsigned short hh = f2bf_hi(ureg[q][e]);
                hv[e] = (short)hh;
                lv[e] = (short)f2bf(ureg[q][e] - bf2f(hh));
            }
            *(bf16x4*)&sU[buf][0][row][hcol] = hv;
            *(bf16x4*)&sU[buf][1][row][hcol] = lv;
        }
        // ---- issue next tile's loads (consumed next iteration) ----
        if (t < 15) {
#pragma unroll
            for (int q = 0; q < 16; ++q)
                ureg[q] = *(const f32x4*)&ub[(size_t)(t + 1) * 16384 + tid * 4 + q * 1024];
        }
        __syncthreads();   // bar1: sU[buf] ready

        // ---- GEMM: bu fragments for this wave's 32 l-rows ----
        f32x4 accr[2][2], acci[2][2];
#pragma unroll
        for (int mi = 0; mi < 2; ++mi)
#pragma unroll
            for (int ni = 0; ni < 2; ++ni) { accr[mi][ni] = (f32x4)(0.f); acci[mi][ni] = (f32x4)(0.f); }

#pragma unroll
        for (int kc = 0; kc < 4; ++kc) {
#pragma unroll
            for (int mi = 0; mi < 2; ++mi) {
                int row = w * 32 + mi * 16 + fr;
                bf16x8 ah = *(const bf16x8*)&sU[buf][0][row][kc * 32 + g * 8];
                bf16x8 al = *(const bf16x8*)&sU[buf][1][row][kc * 32 + g * 8];
#pragma unroll
                for (int ni = 0; ni < 2; ++ni) {
                    accr[mi][ni] = __builtin_amdgcn_mfma_f32_16x16x32_bf16(ah, Bf[0][ni][kc], accr[mi][ni], 0, 0, 0);
                    accr[mi][ni] = __builtin_amdgcn_mfma_f32_16x16x32_bf16(ah, Bf[1][ni][kc], accr[mi][ni], 0, 0, 0);
                    accr[mi][ni] = __builtin_amdgcn_mfma_f32_16x16x32_bf16(al, Bf[0][ni][kc], accr[mi][ni], 0, 0, 0);
                    acci[mi][ni] = __builtin_amdgcn_mfma_f32_16x16x32_bf16(ah, Bf[2][ni][kc], acci[mi][ni], 0, 0, 0);
                    acci[mi][ni] = __builtin_amdgcn_mfma_f32_16x16x32_bf16(ah, Bf[3][ni][kc], acci[mi][ni], 0, 0, 0);
                    acci[mi][ni] = __builtin_amdgcn_mfma_f32_16x16x32_bf16(al, Bf[2][ni][kc], acci[mi][ni], 0, 0, 0);
                }
            }
        }

        // ---- scan, phase 1: local scans + raw wave carry ----
        float Er[2][2], Ei[2][2];
        float Fr[2][2], Fi[2][2];
#pragma unroll
        for (int ni = 0; ni < 2; ++ni) {
            float lr = pw_r[ni][0], li = pw_i[ni][0];
            float Qr[2], Qi[2];
#pragma unroll
            for (int mi = 0; mi < 2; ++mi) {
                float xr = 0.f, xi = 0.f;
#pragma unroll
                for (int r = 0; r < 4; ++r) {
                    float nr = fmaf(lr, xr, fmaf(-li, xi, accr[mi][ni][r]));
                    float nx = fmaf(lr, xi, fmaf(li, xr, acci[mi][ni][r]));
                    xr = nr; xi = nx;
                    accr[mi][ni][r] = xr; acci[mi][ni][r] = xi;
                }
                Qr[mi] = xr; Qi[mi] = xi;
            }
#pragma unroll
            for (int mi = 0; mi < 2; ++mi) {
                float ur = __shfl_up(Qr[mi], 16u, 64);
                float ui = __shfl_up(Qi[mi], 16u, 64);
                if (g >= 1) {
                    Qr[mi] = fmaf(l4r[ni], ur, fmaf(-l4i[ni], ui, Qr[mi]));
                    Qi[mi] = fmaf(l4r[ni], ui, fmaf(l4i[ni], ur, Qi[mi]));
                }
                ur = __shfl_up(Qr[mi], 32u, 64);
                ui = __shfl_up(Qi[mi], 32u, 64);
                if (g >= 2) {
                    Qr[mi] = fmaf(l8r[ni], ur, fmaf(-l8i[ni], ui, Qr[mi]));
                    Qi[mi] = fmaf(l8r[ni], ui, fmaf(l8i[ni], ur, Qi[mi]));
                }
                float er = __shfl_up(Qr[mi], 16u, 64);
                float ei = __shfl_up(Qi[mi], 16u, 64);
                if (g == 0) { er = 0.f; ei = 0.f; }
                Er[mi][ni] = er; Ei[mi][ni] = ei;
                Fr[mi][ni] = __shfl(Qr[mi], fr + 48, 64);
                Fi[mi][ni] = __shfl(Qi[mi], fr + 48, 64);
            }
            float Rr = fmaf(l16r[ni], Fr[0][ni], fmaf(-l16i[ni], Fi[0][ni], Fr[1][ni]));
            float Ri = fmaf(l16r[ni], Fi[0][ni], fmaf(l16i[ni], Fr[0][ni], Fi[1][ni]));
            if (g == 0) { Rld[w][ni][fr][0] = Rr; Rld[w][ni][fr][1] = Ri; }
        }
        __syncthreads();   // bar2: Rld ready

        // ---- scan, phase 2: cross-wave carry, tile carry, corrections, store ----
#pragma unroll
        for (int ni = 0; ni < 2; ++ni) {
            float Wr = TCr[ni], Wi = TCi[ni];
            float Tr = TCr[ni], Ti = TCi[ni];
#pragma unroll
            for (int w2 = 0; w2 < 4; ++w2) {
                float rr = Rld[w2][ni][fr][0], ri = Rld[w2][ni][fr][1];
                float nTr = fmaf(l32r[ni], Tr, fmaf(-l32i[ni], Ti, rr));
                float nTi = fmaf(l32r[ni], Ti, fmaf(l32i[ni], Tr, ri));
                Tr = nTr; Ti = nTi;
                if (w2 < w) {
                    float nWr = fmaf(l32r[ni], Wr, fmaf(-l32i[ni], Wi, rr));
                    float nWi = fmaf(l32r[ni], Wi, fmaf(l32i[ni], Wr, ri));
                    Wr = nWr; Wi = nWi;
                }
            }
            TCr[ni] = Tr; TCi[ni] = Ti;
            float p1r = fmaf(l16r[ni], Wr, fmaf(-l16i[ni], Wi, Fr[0][ni]));
            float p1i = fmaf(l16r[ni], Wi, fmaf(l16i[ni], Wr, Fi[0][ni]));
#pragma unroll
            for (int mi = 0; mi < 2; ++mi) {
                float prr = (mi == 0) ? Wr : p1r;
                float pri = (mi == 0) ? Wi : p1i;
                float Mr = fmaf(lg_r[ni], prr, fmaf(-lg_i[ni], pri, Er[mi][ni]));
                float Mi = fmaf(lg_r[ni], pri, fmaf(lg_i[ni], prr, Ei[mi][ni]));
#pragma unroll
                for (int r = 0; r < 4; ++r) {
                    accr[mi][ni][r] = fmaf(pw_r[ni][r], Mr, fmaf(-pw_i[ni][r], Mi, accr[mi][ni][r]));
                    acci[mi][ni][r] = fmaf(pw_r[ni][r], Mi, fmaf(pw_i[ni][r], Mr, acci[mi][ni][r]));
                }
            }
        }

        // ---- store states as hi/lo bf16 planes ----
#pragma unroll
        for (int mi = 0; mi < 2; ++mi)
#pragma unroll
            for (int ni = 0; ni < 2; ++ni) {
                int pcol = p0 + ni * 16 + fr;
                int lrow = l0t + w * 32 + mi * 16 + g * 4;
                size_t idx = ((size_t)(b * SSM + pcol)) * LEN + lrow;
                bf16x4 rh, rl, ih, il;
#pragma unroll
                for (int e = 0; e < 4; ++e) {
                    unsigned short hh = f2bf_hi(accr[mi][ni][e]);
                    rh[e] = (short)hh; rl[e] = (short)f2bf(accr[mi][ni][e] - bf2f(hh));
                    hh = f2bf_hi(acci[mi][ni][e]);
                    ih[e] = (short)hh; il[e] = (short)f2bf(acci[mi][ni][e] - bf2f(hh));
                }
                *(bf16x4*)&planes[0 * PLz + idx] = rh;
                *(bf16x4*)&planes[1 * PLz + idx] = rl;
                *(bf16x4*)&planes[2 * PLz + idx] = ih;
                *(bf16x4*)&planes[3 * PLz + idx] = il;
            }
    }
}

// ---------------------------------------------------------------------------
// K3 (MFMA): out[b][l][h] = sum_p s_re*C_re - s_im*C_im + u*D
// Same body as verified round-3; 1D grid with same-b XCD swizzle.
// ---------------------------------------------------------------------------
__global__ __launch_bounds__(256) void k3_out(const unsigned short* __restrict__ planes,
                                              const unsigned short* __restrict__ Csp,
                                              const float* __restrict__ u,
                                              const float* __restrict__ D,
                                              float* __restrict__ out) {
    __shared__ __align__(16) unsigned short sA[4][128][40];
    __shared__ __align__(16) unsigned short sC[4][128][40];
    int d   = blockIdx.x;           // 0..511
    int xcd = d & 7;
    int grp = d >> 3;               // 0..63
    int lt  = grp & 15;
    int bhi = grp >> 4;             // 0..3
    int b   = bhi * 8 + xcd;
    int l0  = lt * 128;

    int tid = threadIdx.x;
    int lane = tid & 63, w = tid >> 6;
    int wl = w >> 1, wh = w & 1;
    int fr = lane & 15, g = lane >> 4;

    f32x4 acc[4][4];
#pragma unroll
    for (int mi = 0; mi < 4; ++mi)
#pragma unroll
        for (int ni = 0; ni < 4; ++ni) acc[mi][ni] = (f32x4)(0.f);

    float dv[4];
#pragma unroll
    for (int ni = 0; ni < 4; ++ni) dv[ni] = D[wh * 64 + ni * 16 + fr];

    for (int pc = 0; pc < SSM; pc += 32) {
        {
            int loct = tid & 15;
#pragma unroll
            for (int r = 0; r < 2; ++r) {
                int p_ = (tid >> 4) + 16 * r;
                int rot = (loct + p_) & 7;
#pragma unroll
                for (int pl = 0; pl < 4; ++pl) {
                    union { bf16x8 v; unsigned long long q[2]; } U;
                    U.v = *(const bf16x8*)&planes[(size_t)pl * PLz +
                            ((size_t)(b * SSM + pc + p_)) * LEN + l0 + loct * 8];
                    unsigned long long x0 = U.q[0], x1 = U.q[1];
                    if (rot & 4) { unsigned long long tq = x0; x0 = x1; x1 = tq; }
                    if (rot & 2) {
                        unsigned long long n0 = (x0 >> 32) | (x1 << 32);
                        unsigned long long n1 = (x1 >> 32) | (x0 << 32);
                        x0 = n0; x1 = n1;
                    }
                    if (rot & 1) {
                        unsigned long long n0 = (x0 >> 16) | (x1 << 48);
                        unsigned long long n1 = (x1 >> 16) | (x0 << 48);
                        x0 = n0; x1 = n1;
                    }
                    int rb = loct * 8;
                    sA[pl][rb + ((0 + rot) & 7)][p_] = (unsigned short)(x0);
                    sA[pl][rb + ((1 + rot) & 7)][p_] = (unsigned short)(x0 >> 16);
                    sA[pl][rb + ((2 + rot) & 7)][p_] = (unsigned short)(x0 >> 32);
                    sA[pl][rb + ((3 + rot) & 7)][p_] = (unsigned short)(x0 >> 48);
                    sA[pl][rb + ((4 + rot) & 7)][p_] = (unsigned short)(x1);
                    sA[pl][rb + ((5 + rot) & 7)][p_] = (unsigned short)(x1 >> 16);
                    sA[pl][rb + ((6 + rot) & 7)][p_] = (unsigned short)(x1 >> 32);
                    sA[pl][rb + ((7 + rot) & 7)][p_] = (unsigned short)(x1 >> 48);
                }
            }
        }
        {
            int poct = tid & 3;
#pragma unroll
            for (int r2 = 0; r2 < 2; ++r2) {
                int hh = (tid >> 2) + 64 * r2;
#pragma unroll
                for (int pl = 0; pl < 4; ++pl) {
                    i32x4 v = *(const i32x4*)&Csp[(size_t)pl * CPL + (size_t)hh * SSM + pc + poct * 8];
                    *(i32x4*)&sC[pl][hh][poct * 8] = v;
                }
            }
        }
        __syncthreads();

        int kk = g * 8;
        bf16x8 crh[4], crl[4], cih[4], cil[4];
#pragma unroll
        for (int ni = 0; ni < 4; ++ni) {
            int hr = wh * 64 + ni * 16 + fr;
            crh[ni] = *(const bf16x8*)&sC[0][hr][kk];
            crl[ni] = *(const bf16x8*)&sC[1][hr][kk];
            cih[ni] = *(const bf16x8*)&sC[2][hr][kk];
            cil[ni] = *(const bf16x8*)&sC[3][hr][kk];
        }
#pragma unroll
        for (int mi = 0; mi < 4; ++mi) {
            int lr_ = wl * 64 + mi * 16 + fr;
            bf16x8 arh = *(const bf16x8*)&sA[0][lr_][kk];
            bf16x8 arl = *(const bf16x8*)&sA[1][lr_][kk];
            bf16x8 aih = *(const bf16x8*)&sA[2][lr_][kk];
            bf16x8 ail = *(const bf16x8*)&sA[3][lr_][kk];
#pragma unroll
            for (int ni = 0; ni < 4; ++ni) {
                acc[mi][ni] = __builtin_amdgcn_mfma_f32_16x16x32_bf16(arh, crh[ni], acc[mi][ni], 0, 0, 0);
                acc[mi][ni] = __builtin_amdgcn_mfma_f32_16x16x32_bf16(arh, crl[ni], acc[mi][ni], 0, 0, 0);
                acc[mi][ni] = __builtin_amdgcn_mfma_f32_16x16x32_bf16(arl, crh[ni], acc[mi][ni], 0, 0, 0);
                acc[mi][ni] = __builtin_amdgcn_mfma_f32_16x16x32_bf16(aih, cih[ni], acc[mi][ni], 0, 0, 0);
                acc[mi][ni] = __builtin_amdgcn_mfma_f32_16x16x32_bf16(aih, cil[ni], acc[mi][ni], 0, 0, 0);
                acc[mi][ni] = __builtin_amdgcn_mfma_f32_16x16x32_bf16(ail, cih[ni], acc[mi][ni], 0, 0, 0);
            }
        }
        __syncthreads();
    }

#pragma unroll
    for (int mi = 0; mi < 4; ++mi)
#pragma unroll
        for (int ni = 0; ni < 4; ++ni) {
            int lb = l0 + wl * 64 + mi * 16 + g * 4;
            int h = wh * 64 + ni * 16 + fr;
#pragma unroll
            for (int r = 0; r < 4; ++r) {
                size_t idx = ((size_t)b * LEN + lb + r) * HID + h;
                out[idx] = acc[mi][ni][r] + u[idx] * dv[ni];
            }
        }
}

// ---------------------------------------------------------------------------
// Workspace layout (bytes):
//   [0, 134217728)             4 bf16 state planes
//   [134217728, 134219776)     lam (512 f32)
//   [134219776, 134481920)     B split planes (4 x 32768 ushort)
//   [134481920, 134744064)     C split planes (4 x 32768 ushort)
// ---------------------------------------------------------------------------
extern "C" void kernel_launch(void* const* d_in, const int* in_sizes, int n_in,
                              void* d_out, int out_size, void* d_ws, size_t ws_size,
                              hipStream_t stream) {
    const float* u  = (const float*)d_in[0];
    const float* A  = (const float*)d_in[1];
    const float* G  = (const float*)d_in[2];
    const float* st = (const float*)d_in[3];
    const float* B  = (const float*)d_in[4];
    const float* C  = (const float*)d_in[5];
    const float* D  = (const float*)d_in[6];
    float* out = (float*)d_out;

    char* WS = (char*)d_ws;
    unsigned short* planes = (unsigned short*)WS;
    float* lam             = (float*)(WS + 134217728);
    unsigned short* Bsp    = (unsigned short*)(WS + 134219776);
    unsigned short* Csp    = (unsigned short*)(WS + 134481920);

    k0_params<<<1, 256, 0, stream>>>(A, G, st, lam);
    k0b_prep<<<256, 256, 0, stream>>>(B, C, Bsp, Csp);
    k12_fused<<<256, 256, 0, stream>>>(u, Bsp, lam, planes);
    k3_out<<<512, 256, 0, stream>>>(planes, Csp, u, D, out);
}

// Round 5
// 123.756 us; speedup vs baseline: 1.3770x; 1.1712x over previous
//
#include <hip/hip_runtime.h>
#include <math.h>

#define BATCH 32
#define LEN   2048
#define HID   128
#define SSM   256

static const size_t PLz = 16777216;   // elements per state plane (32*256*2048)
#define BPL 32768                     // elements per B-split plane (256*128)
#define CPL 32768                     // elements per C-split plane (128*256)

typedef __attribute__((ext_vector_type(4))) float f32x4;
typedef __attribute__((ext_vector_type(8))) short bf16x8;
typedef __attribute__((ext_vector_type(4))) short bf16x4;
typedef __attribute__((ext_vector_type(4))) int   i32x4;

// RNE f32->bf16 (lo terms)
static __device__ __forceinline__ unsigned short f2bf(float x) {
    union { float f; unsigned u; } v; v.f = x;
    unsigned r = (v.u + 0x7FFFu + ((v.u >> 16) & 1u)) >> 16;
    return (unsigned short)r;
}
// truncating f32->bf16 (hi term; lo captures remainder exactly)
static __device__ __forceinline__ unsigned short f2bf_hi(float x) {
    union { float f; unsigned u; } v; v.f = x;
    return (unsigned short)(v.u >> 16);
}
static __device__ __forceinline__ float bf2f(unsigned short b) {
    union { unsigned u; float f; } v; v.u = ((unsigned)b) << 16;
    return v.f;
}
static __device__ __forceinline__ void cmul(float& rr, float& ri,
                                            float ar, float ai, float br, float bi) {
    rr = ar * br - ai * bi;
    ri = ar * bi + ai * br;
}

// ---------------------------------------------------------------------------
// K0: parameter projection + eigenvalue. lam[0..255]=re, lam[256..511]=im.
// ---------------------------------------------------------------------------
__global__ void k0_params(const float* __restrict__ A, const float* __restrict__ G,
                          const float* __restrict__ steps, float* __restrict__ lam) {
    int p = threadIdx.x;
    if (p < SSM) {
        float stp   = 1.f / (1.f + expf(-steps[p]));
        float g     = fmaxf(G[p], 0.f);
        float denom = fmaxf(stp * stp, 1e-6f);
        float s     = stp * g;
        float base  = sqrtf(fmaxf(1.f + s, 1e-6f));
        float alow  = (2.f + s - 2.f * base) / denom;
        float ahigh = (2.f + s + 2.f * base) / denom;
        float a     = alow + fmaxf(A[p] - alow, 0.f) - fmaxf(A[p] - ahigh, 0.f);
        float S     = 1.f / (1.f + stp * g);
        float T     = S + 1.f - stp * stp * S * a;
        lam[p]       = 0.5f * T;
        lam[SSM + p] = sqrtf(fmaxf(S - 0.25f * T * T, 0.f));
    }
}

// ---------------------------------------------------------------------------
// K0b: pre-split B and C into hi/lo bf16 planes.
// Bsp planes: [re_hi, re_lo, im_hi, im_lo], layout [p][h]
// Csp planes: [re_hi, re_lo, nim_hi, nim_lo] (imag NEGATED), layout [h][p]
// ---------------------------------------------------------------------------
__global__ __launch_bounds__(256) void k0b_prep(const float* __restrict__ Bm,
                                                const float* __restrict__ Cm,
                                                unsigned short* __restrict__ Bsp,
                                                unsigned short* __restrict__ Csp) {
    int gidx = blockIdx.x * 256 + threadIdx.x;
    if (gidx < 32768) {
        int p = gidx >> 7, h = gidx & 127;
        float vr = Bm[(size_t)(p * HID + h) * 2];
        float vi = Bm[(size_t)(p * HID + h) * 2 + 1];
        unsigned short hh = f2bf_hi(vr);
        Bsp[0 * BPL + p * HID + h] = hh;
        Bsp[1 * BPL + p * HID + h] = f2bf(vr - bf2f(hh));
        hh = f2bf_hi(vi);
        Bsp[2 * BPL + p * HID + h] = hh;
        Bsp[3 * BPL + p * HID + h] = f2bf(vi - bf2f(hh));
    } else {
        int g2 = gidx - 32768;
        int h = g2 >> 8, p = g2 & 255;
        float vr = Cm[(size_t)(h * SSM + p) * 2];
        float vi = -Cm[(size_t)(h * SSM + p) * 2 + 1];
        unsigned short hh = f2bf_hi(vr);
        Csp[0 * CPL + h * SSM + p] = hh;
        Csp[1 * CPL + h * SSM + p] = f2bf(vr - bf2f(hh));
        hh = f2bf_hi(vi);
        Csp[2 * CPL + h * SSM + p] = hh;
        Csp[3 * CPL + h * SSM + p] = f2bf(vi - bf2f(hh));
    }
}

// ---------------------------------------------------------------------------
// K12 v2: per block = (16 p-columns, one b); 512 blocks -> 2 blocks/CU.
// 16 l-tiles of 128. Single sU (64 KB, XOR-swizzled byte^=(row&7)<<4),
// aliased with the store-transpose buffer sT (barrier-ordered).
// Per tile: convert -> barB -> [issue t+1 loads] GEMM(48 MFMA) + scan ph1
// -> barC -> scan ph2 + split -> sT ds_writes -> barD -> coalesced stores
// -> barA. Scan math identical to verified round-3/4.
// ---------------------------------------------------------------------------
__global__ __launch_bounds__(256, 2) void k12_fused(const float* __restrict__ u,
                                                    const unsigned short* __restrict__ Bsp,
                                                    const float* __restrict__ lam,
                                                    unsigned short* __restrict__ planes) {
    __shared__ __align__(16) char smem[65536];   // sU (2 planes x 128 x 256B) | sT alias
    __shared__ float Rld[4][16][2];

    int d    = blockIdx.x;           // 0..511
    int xcd  = d & 7;
    int pt   = (d >> 3) & 15;
    int bhi  = d >> 7;               // 0..3
    int b    = bhi * 8 + xcd;
    int p0   = pt * 16;

    int tid  = threadIdx.x;
    int lane = tid & 63, w = tid >> 6;
    int fr   = lane & 15, g = lane >> 4;

    // ---- B fragments -> registers: [plane][kchunk] (p = p0 + fr) ----
    bf16x8 Bf[4][4];
#pragma unroll
    for (int pl = 0; pl < 4; ++pl)
#pragma unroll
        for (int kc = 0; kc < 4; ++kc)
            Bf[pl][kc] = *(const bf16x8*)&Bsp[(size_t)pl * BPL +
                    (size_t)(p0 + fr) * HID + kc * 32 + g * 8];

    // ---- lambda powers for this lane's p-column ----
    float pw_r[4], pw_i[4];
    float lg_r, lg_i;
    float l4r, l4i, l8r, l8i, l16r, l16i, l32r, l32i;
    {
        int p = p0 + fr;
        float ar = lam[p], ai = lam[SSM + p];
        pw_r[0] = ar; pw_i[0] = ai;
        cmul(pw_r[1], pw_i[1], ar, ai, ar, ai);
        cmul(pw_r[2], pw_i[2], pw_r[1], pw_i[1], ar, ai);
        cmul(pw_r[3], pw_i[3], pw_r[1], pw_i[1], pw_r[1], pw_i[1]);
        l4r = pw_r[3]; l4i = pw_i[3];
        cmul(l8r, l8i, l4r, l4i, l4r, l4i);
        cmul(l16r, l16i, l8r, l8i, l8r, l8i);
        cmul(l32r, l32i, l16r, l16i, l16r, l16i);
        if (g == 0)      { lg_r = 1.f; lg_i = 0.f; }
        else if (g == 1) { lg_r = l4r; lg_i = l4i; }
        else if (g == 2) { lg_r = l8r; lg_i = l8i; }
        else             { cmul(lg_r, lg_i, l8r, l8i, l4r, l4i); }
    }

    float TCr = 0.f, TCi = 0.f;      // running tile carry

    const float* ub = u + (size_t)b * (LEN * HID);
    int srow  = tid >> 5;            // 0..7 (== row&7 for all its rows)
    int swzW  = srow << 4;           // write-side XOR
    int wcol8 = (tid & 31) * 8;      // byte col of this thread's 8B piece

    // ---- prologue: tile 0 loads ----
    f32x4 ureg[16];
#pragma unroll
    for (int q = 0; q < 16; ++q)
        ureg[q] = *(const f32x4*)&ub[tid * 4 + q * 1024];

    for (int t = 0; t < 16; ++t) {
        int l0t = t * 128;

        // ---- convert ureg (tile t) -> sU hi/lo (swizzled) ----
#pragma unroll
        for (int q = 0; q < 16; ++q) {
            int row = srow + 8 * q;
            bf16x4 hv, lv;
#pragma unroll
            for (int e = 0; e < 4; ++e) {
                unsigned short hh = f2bf_hi(ureg[q][e]);
                hv[e] = (short)hh;
                lv[e] = (short)f2bf(ureg[q][e] - bf2f(hh));
            }
            int off = row * 256 + (wcol8 ^ swzW);
            *(bf16x4*)(smem + off)         = hv;   // hi plane
            *(bf16x4*)(smem + 32768 + off) = lv;   // lo plane
        }
        __syncthreads();   // barB: sU ready

        // ---- issue next tile's loads (drained at barC, hidden under GEMM+scan) ----
        if (t < 15) {
#pragma unroll
            for (int q = 0; q < 16; ++q)
                ureg[q] = *(const f32x4*)&ub[(size_t)(t + 1) * 16384 + tid * 4 + q * 1024];
        }

        // ---- GEMM: bu fragments for this wave's 32 l-rows ----
        f32x4 accr[2], acci[2];
        accr[0] = (f32x4)(0.f); accr[1] = (f32x4)(0.f);
        acci[0] = (f32x4)(0.f); acci[1] = (f32x4)(0.f);
#pragma unroll
        for (int kc = 0; kc < 4; ++kc) {
#pragma unroll
            for (int mi = 0; mi < 2; ++mi) {
                int row = w * 32 + mi * 16 + fr;
                int off = row * 256 + ((kc * 64 + g * 16) ^ ((fr & 7) << 4));
                bf16x8 ah = *(const bf16x8*)(smem + off);
                bf16x8 al = *(const bf16x8*)(smem + 32768 + off);
                accr[mi] = __builtin_amdgcn_mfma_f32_16x16x32_bf16(ah, Bf[0][kc], accr[mi], 0, 0, 0);
                accr[mi] = __builtin_amdgcn_mfma_f32_16x16x32_bf16(ah, Bf[1][kc], accr[mi], 0, 0, 0);
                accr[mi] = __builtin_amdgcn_mfma_f32_16x16x32_bf16(al, Bf[0][kc], accr[mi], 0, 0, 0);
                acci[mi] = __builtin_amdgcn_mfma_f32_16x16x32_bf16(ah, Bf[2][kc], acci[mi], 0, 0, 0);
                acci[mi] = __builtin_amdgcn_mfma_f32_16x16x32_bf16(ah, Bf[3][kc], acci[mi], 0, 0, 0);
                acci[mi] = __builtin_amdgcn_mfma_f32_16x16x32_bf16(al, Bf[2][kc], acci[mi], 0, 0, 0);
            }
        }

        // ---- scan phase 1: local scans + raw wave carry ----
        float Er[2], Ei[2], Fr[2], Fi[2];
        {
            float lr = pw_r[0], li = pw_i[0];
            float Qr[2], Qi[2];
#pragma unroll
            for (int mi = 0; mi < 2; ++mi) {
                float xr = 0.f, xi = 0.f;
#pragma unroll
                for (int r = 0; r < 4; ++r) {
                    float nr = fmaf(lr, xr, fmaf(-li, xi, accr[mi][r]));
                    float nx = fmaf(lr, xi, fmaf(li, xr, acci[mi][r]));
                    xr = nr; xi = nx;
                    accr[mi][r] = xr; acci[mi][r] = xi;
                }
                Qr[mi] = xr; Qi[mi] = xi;
            }
#pragma unroll
            for (int mi = 0; mi < 2; ++mi) {
                float ur = __shfl_up(Qr[mi], 16u, 64);
                float ui = __shfl_up(Qi[mi], 16u, 64);
                if (g >= 1) {
                    Qr[mi] = fmaf(l4r, ur, fmaf(-l4i, ui, Qr[mi]));
                    Qi[mi] = fmaf(l4r, ui, fmaf(l4i, ur, Qi[mi]));
                }
                ur = __shfl_up(Qr[mi], 32u, 64);
                ui = __shfl_up(Qi[mi], 32u, 64);
                if (g >= 2) {
                    Qr[mi] = fmaf(l8r, ur, fmaf(-l8i, ui, Qr[mi]));
                    Qi[mi] = fmaf(l8r, ui, fmaf(l8i, ur, Qi[mi]));
                }
                float er = __shfl_up(Qr[mi], 16u, 64);
                float ei = __shfl_up(Qi[mi], 16u, 64);
                if (g == 0) { er = 0.f; ei = 0.f; }
                Er[mi] = er; Ei[mi] = ei;
                Fr[mi] = __shfl(Qr[mi], fr + 48, 64);
                Fi[mi] = __shfl(Qi[mi], fr + 48, 64);
            }
            float Rr = fmaf(l16r, Fr[0], fmaf(-l16i, Fi[0], Fr[1]));
            float Ri = fmaf(l16r, Fi[0], fmaf(l16i, Fr[0], Fi[1]));
            if (g == 0) { Rld[w][fr][0] = Rr; Rld[w][fr][1] = Ri; }
        }
        __syncthreads();   // barC: Rld ready, sU reads done, ureg loads drained

        // ---- scan phase 2: cross-wave carry, tile carry, corrections ----
        {
            float Wr = TCr, Wi = TCi;
            float Tr = TCr, Ti = TCi;
#pragma unroll
            for (int w2 = 0; w2 < 4; ++w2) {
                float rr = Rld[w2][fr][0], ri = Rld[w2][fr][1];
                float nTr = fmaf(l32r, Tr, fmaf(-l32i, Ti, rr));
                float nTi = fmaf(l32r, Ti, fmaf(l32i, Tr, ri));
                Tr = nTr; Ti = nTi;
                if (w2 < w) {
                    float nWr = fmaf(l32r, Wr, fmaf(-l32i, Wi, rr));
                    float nWi = fmaf(l32r, Wi, fmaf(l32i, Wr, ri));
                    Wr = nWr; Wi = nWi;
                }
            }
            TCr = Tr; TCi = Ti;
            float p1r = fmaf(l16r, Wr, fmaf(-l16i, Wi, Fr[0]));
            float p1i = fmaf(l16r, Wi, fmaf(l16i, Wr, Fi[0]));
#pragma unroll
            for (int mi = 0; mi < 2; ++mi) {
                float prr = (mi == 0) ? Wr : p1r;
                float pri = (mi == 0) ? Wi : p1i;
                float Mr = fmaf(lg_r, prr, fmaf(-lg_i, pri, Er[mi]));
                float Mi = fmaf(lg_r, pri, fmaf(lg_i, prr, Ei[mi]));
#pragma unroll
                for (int r = 0; r < 4; ++r) {
                    accr[mi][r] = fmaf(pw_r[r], Mr, fmaf(-pw_i[r], Mi, accr[mi][r]));
                    acci[mi][r] = fmaf(pw_r[r], Mi, fmaf(pw_i[r], Mr, acci[mi][r]));
                }
            }
        }

        // ---- split hi/lo and transpose through sT (aliases smem) ----
        // sT layout: [pl][16 p][136 l-pad], ushort
#pragma unroll
        for (int mi = 0; mi < 2; ++mi) {
            int col = w * 32 + mi * 16 + g * 4;
            bf16x4 rh, rl, ih, il;
#pragma unroll
            for (int e = 0; e < 4; ++e) {
                unsigned short hh = f2bf_hi(accr[mi][e]);
                rh[e] = (short)hh; rl[e] = (short)f2bf(accr[mi][e] - bf2f(hh));
                hh = f2bf_hi(acci[mi][e]);
                ih[e] = (short)hh; il[e] = (short)f2bf(acci[mi][e] - bf2f(hh));
            }
            *(bf16x4*)(smem + ((0 * 16 + fr) * 136 + col) * 2) = rh;
            *(bf16x4*)(smem + ((1 * 16 + fr) * 136 + col) * 2) = rl;
            *(bf16x4*)(smem + ((2 * 16 + fr) * 136 + col) * 2) = ih;
            *(bf16x4*)(smem + ((3 * 16 + fr) * 136 + col) * 2) = il;
        }
        __syncthreads();   // barD: sT ready

        // ---- coalesced global stores: 16 threads -> 256B contiguous ----
        {
            int pr = tid >> 4, lc = (tid & 15) * 8;
#pragma unroll
            for (int pl = 0; pl < 4; ++pl) {
                bf16x8 v = *(const bf16x8*)(smem + ((pl * 16 + pr) * 136 + lc) * 2);
                *(bf16x8*)&planes[(size_t)pl * PLz +
                        ((size_t)(b * SSM + p0 + pr)) * LEN + l0t + lc] = v;
            }
        }
        __syncthreads();   // barA: sT reads done, smem free for next convert
    }
}

// ---------------------------------------------------------------------------
// K3 (MFMA): out[b][l][h] = sum_p s_re*C_re - s_im*C_im + u*D   (verified)
// ---------------------------------------------------------------------------
__global__ __launch_bounds__(256) void k3_out(const unsigned short* __restrict__ planes,
                                              const unsigned short* __restrict__ Csp,
                                              const float* __restrict__ u,
                                              const float* __restrict__ D,
                                              float* __restrict__ out) {
    __shared__ __align__(16) unsigned short sA[4][128][40];
    __shared__ __align__(16) unsigned short sC[4][128][40];
    int d   = blockIdx.x;           // 0..511
    int xcd = d & 7;
    int grp = d >> 3;               // 0..63
    int lt  = grp & 15;
    int bhi = grp >> 4;             // 0..3
    int b   = bhi * 8 + xcd;
    int l0  = lt * 128;

    int tid = threadIdx.x;
    int lane = tid & 63, w = tid >> 6;
    int wl = w >> 1, wh = w & 1;
    int fr = lane & 15, g = lane >> 4;

    f32x4 acc[4][4];
#pragma unroll
    for (int mi = 0; mi < 4; ++mi)
#pragma unroll
        for (int ni = 0; ni < 4; ++ni) acc[mi][ni] = (f32x4)(0.f);

    float dv[4];
#pragma unroll
    for (int ni = 0; ni < 4; ++ni) dv[ni] = D[wh * 64 + ni * 16 + fr];

    for (int pc = 0; pc < SSM; pc += 32) {
        {
            int loct = tid & 15;
#pragma unroll
            for (int r = 0; r < 2; ++r) {
                int p_ = (tid >> 4) + 16 * r;
                int rot = (loct + p_) & 7;
#pragma unroll
                for (int pl = 0; pl < 4; ++pl) {
                    union { bf16x8 v; unsigned long long q[2]; } U;
                    U.v = *(const bf16x8*)&planes[(size_t)pl * PLz +
                            ((size_t)(b * SSM + pc + p_)) * LEN + l0 + loct * 8];
                    unsigned long long x0 = U.q[0], x1 = U.q[1];
                    if (rot & 4) { unsigned long long tq = x0; x0 = x1; x1 = tq; }
                    if (rot & 2) {
                        unsigned long long n0 = (x0 >> 32) | (x1 << 32);
                        unsigned long long n1 = (x1 >> 32) | (x0 << 32);
                        x0 = n0; x1 = n1;
                    }
                    if (rot & 1) {
                        unsigned long long n0 = (x0 >> 16) | (x1 << 48);
                        unsigned long long n1 = (x1 >> 16) | (x0 << 48);
                        x0 = n0; x1 = n1;
                    }
                    int rb = loct * 8;
                    sA[pl][rb + ((0 + rot) & 7)][p_] = (unsigned short)(x0);
                    sA[pl][rb + ((1 + rot) & 7)][p_] = (unsigned short)(x0 >> 16);
                    sA[pl][rb + ((2 + rot) & 7)][p_] = (unsigned short)(x0 >> 32);
                    sA[pl][rb + ((3 + rot) & 7)][p_] = (unsigned short)(x0 >> 48);
                    sA[pl][rb + ((4 + rot) & 7)][p_] = (unsigned short)(x1);
                    sA[pl][rb + ((5 + rot) & 7)][p_] = (unsigned short)(x1 >> 16);
                    sA[pl][rb + ((6 + rot) & 7)][p_] = (unsigned short)(x1 >> 32);
                    sA[pl][rb + ((7 + rot) & 7)][p_] = (unsigned short)(x1 >> 48);
                }
            }
        }
        {
            int poct = tid & 3;
#pragma unroll
            for (int r2 = 0; r2 < 2; ++r2) {
                int hh = (tid >> 2) + 64 * r2;
#pragma unroll
                for (int pl = 0; pl < 4; ++pl) {
                    i32x4 v = *(const i32x4*)&Csp[(size_t)pl * CPL + (size_t)hh * SSM + pc + poct * 8];
                    *(i32x4*)&sC[pl][hh][poct * 8] = v;
                }
            }
        }
        __syncthreads();

        int kk = g * 8;
        bf16x8 crh[4], crl[4], cih[4], cil[4];
#pragma unroll
        for (int ni = 0; ni < 4; ++ni) {
            int hr = wh * 64 + ni * 16 + fr;
            crh[ni] = *(const bf16x8*)&sC[0][hr][kk];
            crl[ni] = *(const bf16x8*)&sC[1][hr][kk];
            cih[ni] = *(const bf16x8*)&sC[2][hr][kk];
            cil[ni] = *(const bf16x8*)&sC[3][hr][kk];
        }
#pragma unroll
        for (int mi = 0; mi < 4; ++mi) {
            int lr_ = wl * 64 + mi * 16 + fr;
            bf16x8 arh = *(const bf16x8*)&sA[0][lr_][kk];
            bf16x8 arl = *(const bf16x8*)&sA[1][lr_][kk];
            bf16x8 aih = *(const bf16x8*)&sA[2][lr_][kk];
            bf16x8 ail = *(const bf16x8*)&sA[3][lr_][kk];
#pragma unroll
            for (int ni = 0; ni < 4; ++ni) {
                acc[mi][ni] = __builtin_amdgcn_mfma_f32_16x16x32_bf16(arh, crh[ni], acc[mi][ni], 0, 0, 0);
                acc[mi][ni] = __builtin_amdgcn_mfma_f32_16x16x32_bf16(arh, crl[ni], acc[mi][ni], 0, 0, 0);
                acc[mi][ni] = __builtin_amdgcn_mfma_f32_16x16x32_bf16(arl, crh[ni], acc[mi][ni], 0, 0, 0);
                acc[mi][ni] = __builtin_amdgcn_mfma_f32_16x16x32_bf16(aih, cih[ni], acc[mi][ni], 0, 0, 0);
                acc[mi][ni] = __builtin_amdgcn_mfma_f32_16x16x32_bf16(aih, cil[ni], acc[mi][ni], 0, 0, 0);
                acc[mi][ni] = __builtin_amdgcn_mfma_f32_16x16x32_bf16(ail, cih[ni], acc[mi][ni], 0, 0, 0);
            }
        }
        __syncthreads();
    }

#pragma unroll
    for (int mi = 0; mi < 4; ++mi)
#pragma unroll
        for (int ni = 0; ni < 4; ++ni) {
            int lb = l0 + wl * 64 + mi * 16 + g * 4;
            int h = wh * 64 + ni * 16 + fr;
#pragma unroll
            for (int r = 0; r < 4; ++r) {
                size_t idx = ((size_t)b * LEN + lb + r) * HID + h;
                out[idx] = acc[mi][ni][r] + u[idx] * dv[ni];
            }
        }
}

// ---------------------------------------------------------------------------
// Workspace layout (bytes):
//   [0, 134217728)             4 bf16 state planes
//   [134217728, 134219776)     lam (512 f32)
//   [134219776, 134481920)     B split planes (4 x 32768 ushort)
//   [134481920, 134744064)     C split planes (4 x 32768 ushort)
// ---------------------------------------------------------------------------
extern "C" void kernel_launch(void* const* d_in, const int* in_sizes, int n_in,
                              void* d_out, int out_size, void* d_ws, size_t ws_size,
                              hipStream_t stream) {
    const float* u  = (const float*)d_in[0];
    const float* A  = (const float*)d_in[1];
    const float* G  = (const float*)d_in[2];
    const float* st = (const float*)d_in[3];
    const float* B  = (const float*)d_in[4];
    const float* C  = (const float*)d_in[5];
    const float* D  = (const float*)d_in[6];
    float* out = (float*)d_out;

    char* WS = (char*)d_ws;
    unsigned short* planes = (unsigned short*)WS;
    float* lam             = (float*)(WS + 134217728);
    unsigned short* Bsp    = (unsigned short*)(WS + 134219776);
    unsigned short* Csp    = (unsigned short*)(WS + 134481920);

    k0_params<<<1, 256, 0, stream>>>(A, G, st, lam);
    k0b_prep<<<256, 256, 0, stream>>>(B, C, Bsp, Csp);
    k12_fused<<<512, 256, 0, stream>>>(u, Bsp, lam, planes);
    k3_out<<<512, 256, 0, stream>>>(planes, Csp, u, D, out);
}